// Round 1
// baseline (708.354 us; speedup 1.0000x reference)
//
#include <hip/hip_runtime.h>
#include <math.h>

#define BDIM 8
#define CIN  256
#define COUT 256
#define NDIM 8192

#define NEG_COEF  0.8f
#define LRELU_EPS 1e-6f
#define BN_EPS    1e-5f

typedef __attribute__((ext_vector_type(8))) short bf16x8;   // 8 bf16 = 4 VGPRs
typedef __attribute__((ext_vector_type(4))) float f32x4;

// ws layout:
//   [0, 512KB)        : W fragments (hi/lo, feat/dir), ushort indices below
//   [512KB, 512KB+32K): BN stats scratch (floats)
//   [WS_XHI, +96MB)   : Xhi images, [b][nblk][ctile][12288B], swizzled LDS image
//   [WS_XLO, +96MB)   : Xlo images, same layout
#define WS_WFH 0
#define WS_WFL 65536
#define WS_WDH 131072
#define WS_WDL 196608
#define WS_STATS_BYTE 524288
#define NSLOT 8
#define TILE_BYTES 12288                         // 192 rows x 64 B (32 bf16)
#define WS_XHI_BYTE 557056
#define XIMG_BYTES 100663296ull                  // 8*128*8*12288
#define WS_XLO_BYTE (WS_XHI_BYTE + XIMG_BYTES)
#define WS_NEED (WS_XLO_BYTE + XIMG_BYTES)

__device__ __forceinline__ unsigned short f2bf(float f) {
    unsigned u = __float_as_uint(f);
    return (unsigned short)((u + 0x7FFFu + ((u >> 16) & 1u)) >> 16);
}
__device__ __forceinline__ float bf2f(unsigned short h) {
    return __uint_as_float(((unsigned)h) << 16);
}

// Bank swizzle for the X images: XOR bits 4-6 of the byte offset with bits 6-8
// (= row & 7). Bijective (upper-triangular over GF(2)); maps aligned 16B chunks
// to aligned 16B chunks; spreads 8 consecutive 64B rows across all 8 bank-quads
// so the stride-64B b128 fragment reads are conflict-free.
__device__ __forceinline__ int swz(int off) {
    return off ^ (((off >> 6) & 7) << 4);
}

__device__ __forceinline__ void gl_lds16(const char* g, char* l) {
    __builtin_amdgcn_global_load_lds(
        (const __attribute__((address_space(1))) unsigned int*)g,
        (__attribute__((address_space(3))) unsigned int*)l, 16, 0, 0);
}

// Convert W[o][c] fp32 -> bf16 hi/lo in fragment k-order (pos = 4*(c&7) + ((c>>3)&3)
// within each 32-k tile). Applied identically to A and B sides -> dot invariant.
__global__ __launch_bounds__(256) void setup_w_kernel(
    const float* __restrict__ Wf, const float* __restrict__ Wd,
    unsigned short* __restrict__ wsu)
{
    const int o = blockIdx.x;
    const int mat = blockIdx.y;
    const int c = threadIdx.x;
    const float* W = mat ? Wd : Wf;
    float w = W[o * CIN + c];
    unsigned short hi = f2bf(w);
    unsigned short lo = f2bf(w - bf2f(hi));
    int pos = (c & ~31) + 4 * (c & 7) + ((c >> 3) & 3);
    unsigned short* ph = wsu + (mat ? WS_WDH : WS_WFH);
    unsigned short* pl = wsu + (mat ? WS_WDL : WS_WFL);
    ph[o * CIN + pos] = hi;
    pl[o * CIN + pos] = lo;
}

// ---------------------------------------------------------------------------
// FAST PATH kernel 1: fused convert + stats.
// Grid (128 nblk, 1, 8 b), 512 threads. Each block owns one (b, 64-n) slice:
//  - converts x fp32 -> bf16 hi/lo ONCE (no o-redundancy),
//  - writes the swizzled LDS image to ws (main kernel DMAs it back linearly),
//  - computes hi-product norms for ALL 256 output channels (wave w: o in [32w,32w+32)).
// ---------------------------------------------------------------------------
__global__ __launch_bounds__(512) void vn_statscvt(
    const float* __restrict__ x, const unsigned short* __restrict__ wsu,
    char* __restrict__ xh, char* __restrict__ xl,
    float* __restrict__ stats)
{
    __shared__ uint4 sH4[TILE_BYTES / 16];
    __shared__ uint4 sL4[TILE_BYTES / 16];
    __shared__ float redS[256], redQ[256];
    char* sH = (char*)sH4;
    char* sL = (char*)sL4;

    const int t    = threadIdx.x;
    const int nblk = blockIdx.x;
    const int b    = blockIdx.z;
    const int n0   = nblk * 64;

    const int lane = t & 63;
    const int w    = t >> 6;        // 0..7
    const int q    = lane >> 4;
    const int ln   = lane & 15;

    const int jl = t & 31;          // staging n-lane
    const int kb = (t >> 5) & 7;    // staging k-base
    const int u  = t >> 8;          // staging ip-half (wave-uniform)

    if (t < 256) { redS[t] = 0.f; redQ[t] = 0.f; }

    f32x4 acc[2][12];
    #pragma unroll
    for (int i = 0; i < 2; ++i)
        #pragma unroll
        for (int j = 0; j < 12; ++j) acc[i][j] = (f32x4)0.f;

    const unsigned short* wfh = wsu + WS_WFH;
    const int oo = w * 32;
    char* ghb = xh + ((size_t)(b * 128 + nblk)) * (8 * TILE_BYTES);
    char* glb = xl + ((size_t)(b * 128 + nblk)) * (8 * TILE_BYTES);

    for (int ct = 0; ct < 8; ++ct) {
        const int c0 = ct * 32;
        __syncthreads();   // all waves done reading previous tile's LDS
        #pragma unroll
        for (int s = 0; s < 3; ++s) {
            const int ip = u * 3 + s;
            const int jloc = ip * 32 + jl;
            const int d = jloc >> 6, nl = jloc & 63;
            float v[4];
            #pragma unroll
            for (int i = 0; i < 4; ++i) {
                int c = c0 + kb + 8 * i;
                v[i] = x[((size_t)((b * CIN + c) * 3 + d)) * NDIM + n0 + nl];
            }
            unsigned short h0 = f2bf(v[0]), h1 = f2bf(v[1]), h2 = f2bf(v[2]), h3 = f2bf(v[3]);
            uint2 ph = make_uint2((unsigned)h0 | ((unsigned)h1 << 16),
                                  (unsigned)h2 | ((unsigned)h3 << 16));
            uint2 pl = make_uint2(
                (unsigned)f2bf(v[0] - bf2f(h0)) | ((unsigned)f2bf(v[1] - bf2f(h1)) << 16),
                (unsigned)f2bf(v[2] - bf2f(h2)) | ((unsigned)f2bf(v[3] - bf2f(h3)) << 16));
            const int off = swz(jloc * 64 + kb * 8);
            *(uint2*)(sH + off) = ph;
            *(uint2*)(sL + off) = pl;
        }
        __syncthreads();
        // LDS -> ws copy, linear (image stored swizzled). 48B per thread:
        // threads 0..255 cover the 12KB hi image exactly, 256..511 the lo image.
        {
            const int off = t * 48;
            const char* src = (off < TILE_BYTES) ? (sH + off) : (sL + off - TILE_BYTES);
            char* dst = (off < TILE_BYTES) ? (ghb + ct * TILE_BYTES + off)
                                           : (glb + ct * TILE_BYTES + off - TILE_BYTES);
            #pragma unroll
            for (int p = 0; p < 3; ++p)
                *(uint4*)(dst + p * 16) = *(const uint4*)(src + p * 16);
        }
        // hi-product MFMA for this wave's 32 channels over all 192 cols
        bf16x8 af[2];
        #pragma unroll
        for (int mt = 0; mt < 2; ++mt)
            af[mt] = *(const bf16x8*)&wfh[(oo + mt * 16 + ln) * CIN + c0 + q * 8];
        #pragma unroll
        for (int nt = 0; nt < 12; ++nt) {
            const int jloc = nt * 16 + ln;
            bf16x8 bh = *(const bf16x8*)(sH + swz(jloc * 64 + q * 16));
            #pragma unroll
            for (int mt = 0; mt < 2; ++mt)
                acc[mt][nt] = __builtin_amdgcn_mfma_f32_16x16x32_bf16(af[mt], bh, acc[mt][nt], 0, 0, 0);
        }
    }

    // norms: nt = d*4 + h (d = nt>>2 since 4 16-col tiles per d)
    #pragma unroll
    for (int mt = 0; mt < 2; ++mt) {
        #pragma unroll
        for (int r = 0; r < 4; ++r) {
            float s = 0.f, s2 = 0.f;
            #pragma unroll
            for (int h = 0; h < 4; ++h) {
                float p0 = acc[mt][0 + h][r];
                float p1 = acc[mt][4 + h][r];
                float p2 = acc[mt][8 + h][r];
                float n2 = p0 * p0 + p1 * p1 + p2 * p2;
                s += sqrtf(n2); s2 += n2;
            }
            #pragma unroll
            for (int m = 1; m < 16; m <<= 1) {
                s  += __shfl_xor(s,  m, 64);
                s2 += __shfl_xor(s2, m, 64);
            }
            if (ln == 0) {
                int o = oo + mt * 16 + q * 4 + r;
                atomicAdd(&redS[o], s);
                atomicAdd(&redQ[o], s2);
            }
        }
    }
    __syncthreads();
    if (t < 256) {
        int slot = nblk & (NSLOT - 1);
        atomicAdd(&stats[slot * 256 + t], redS[t]);
        atomicAdd(&stats[NSLOT * 256 + slot * 256 + t], redQ[t]);
    }
}

__global__ __launch_bounds__(256) void vn_finalize2(
    float* __restrict__ stats, const float* __restrict__ gamma)
{
    int o = threadIdx.x;
    float s = 0.f, s2 = 0.f;
    #pragma unroll
    for (int i = 0; i < NSLOT; ++i) {
        s  += stats[i * 256 + o];
        s2 += stats[(NSLOT + i) * 256 + o];
    }
    const float inv = 1.0f / (float)(BDIM * NDIM);
    float mean = s * inv;
    float var  = fmaxf(s2 * inv - mean * mean, 0.f);
    stats[2 * NSLOT * 256 + o] = mean;
    stats[2 * NSLOT * 256 + 256 + o] = gamma[o] * rsqrtf(var + BN_EPS);
}

// ---------------------------------------------------------------------------
// FAST PATH kernel 2: main. Staging is pure global_load_lds DMA from the
// precomputed swizzled images (no conversion VALU). Grid (128, 4, 8), 256 thr.
// ---------------------------------------------------------------------------
__global__ __launch_bounds__(256) void vn_main2(
    const unsigned short* __restrict__ wsu,
    const char* __restrict__ xh, const char* __restrict__ xl,
    const float* __restrict__ stats, const float* __restrict__ beta,
    float* __restrict__ out)
{
    __shared__ uint4 sH4[TILE_BYTES / 16];
    __shared__ uint4 sL4[TILE_BYTES / 16];
    char* sH = (char*)sH4;
    char* sL = (char*)sL4;

    const int t    = threadIdx.x;
    const int nblk = blockIdx.x;
    const int n0   = nblk * 64;
    const int o0   = blockIdx.y * 64;
    const int b    = blockIdx.z;

    const int lane = t & 63;
    const int w    = t >> 6;
    const int q    = lane >> 4;
    const int ln   = lane & 15;

    f32x4 accP[2][6], accD[2][6];
    #pragma unroll
    for (int i = 0; i < 2; ++i)
        #pragma unroll
        for (int j = 0; j < 6; ++j) { accP[i][j] = (f32x4)0.f; accD[i][j] = (f32x4)0.f; }

    const unsigned short* wfh = wsu + WS_WFH;
    const unsigned short* wfl = wsu + WS_WFL;
    const unsigned short* wdh = wsu + WS_WDH;
    const unsigned short* wdl = wsu + WS_WDL;
    const int oo = o0 + (w >> 1) * 32;
    const int nb = (w & 1) * 32;

    const char* ghb = xh + ((size_t)(b * 128 + nblk)) * (8 * TILE_BYTES);
    const char* glb = xl + ((size_t)(b * 128 + nblk)) * (8 * TILE_BYTES);

    for (int ct = 0; ct < 8; ++ct) {
        __syncthreads();   // all waves done reading previous tile
        #pragma unroll
        for (int p = 0; p < 3; ++p) {
            gl_lds16(ghb + ct * TILE_BYTES + t * 16 + p * 4096, sH + t * 16 + p * 4096);
            gl_lds16(glb + ct * TILE_BYTES + t * 16 + p * 4096, sL + t * 16 + p * 4096);
        }
        __syncthreads();   // vmcnt(0) drain -> LDS image ready

        const int c0 = ct * 32;
        bf16x8 afh[2], afl[2], adh[2], adl[2];
        #pragma unroll
        for (int mt = 0; mt < 2; ++mt) {
            const int row = (oo + mt * 16 + ln) * CIN + c0 + q * 8;
            afh[mt] = *(const bf16x8*)&wfh[row];
            afl[mt] = *(const bf16x8*)&wfl[row];
            adh[mt] = *(const bf16x8*)&wdh[row];
            adl[mt] = *(const bf16x8*)&wdl[row];
        }
        #pragma unroll
        for (int nt = 0; nt < 6; ++nt) {
            const int d = nt >> 1, h = nt & 1;
            const int jloc = d * 64 + nb + h * 16 + ln;
            const int off = swz(jloc * 64 + q * 16);
            bf16x8 bh = *(const bf16x8*)(sH + off);
            bf16x8 bl = *(const bf16x8*)(sL + off);
            #pragma unroll
            for (int mt = 0; mt < 2; ++mt) {
                f32x4 aP = accP[mt][nt];
                aP = __builtin_amdgcn_mfma_f32_16x16x32_bf16(afh[mt], bh, aP, 0, 0, 0);
                aP = __builtin_amdgcn_mfma_f32_16x16x32_bf16(afh[mt], bl, aP, 0, 0, 0);
                aP = __builtin_amdgcn_mfma_f32_16x16x32_bf16(afl[mt], bh, aP, 0, 0, 0);
                aP = __builtin_amdgcn_mfma_f32_16x16x32_bf16(afl[mt], bl, aP, 0, 0, 0);
                accP[mt][nt] = aP;
                f32x4 aD = accD[mt][nt];
                aD = __builtin_amdgcn_mfma_f32_16x16x32_bf16(adh[mt], bh, aD, 0, 0, 0);
                aD = __builtin_amdgcn_mfma_f32_16x16x32_bf16(adh[mt], bl, aD, 0, 0, 0);
                aD = __builtin_amdgcn_mfma_f32_16x16x32_bf16(adl[mt], bh, aD, 0, 0, 0);
                accD[mt][nt] = aD;
            }
        }
    }

    const float* meanp  = stats + 2 * NSLOT * 256;
    const float* scalep = meanp + 256;
    #pragma unroll
    for (int mt = 0; mt < 2; ++mt) {
        #pragma unroll
        for (int r = 0; r < 4; ++r) {
            const int o = oo + mt * 16 + q * 4 + r;
            const float mean  = meanp[o];
            const float scale = scalep[o];
            const float bet   = beta[o];
            #pragma unroll
            for (int h = 0; h < 2; ++h) {
                float p0 = accP[mt][0 + h][r], p1 = accP[mt][2 + h][r], p2 = accP[mt][4 + h][r];
                float d0 = accD[mt][0 + h][r], d1 = accD[mt][2 + h][r], d2 = accD[mt][4 + h][r];
                float n2 = p0 * p0 + p1 * p1 + p2 * p2;
                float nr = sqrtf(n2);
                float f  = ((nr - mean) * scale + bet) / nr;
                p0 *= f; p1 *= f; p2 *= f;
                float dot = p0 * d0 + p1 * d1 + p2 * d2;
                if (dot < 0.f) {
                    float g = NEG_COEF * dot / (d0 * d0 + d1 * d1 + d2 * d2 + LRELU_EPS);
                    p0 -= g * d0; p1 -= g * d1; p2 -= g * d2;
                }
                const int n = n0 + nb + h * 16 + ln;
                out[((size_t)(b * COUT + o) * 3 + 0) * NDIM + n] = p0;
                out[((size_t)(b * COUT + o) * 3 + 1) * NDIM + n] = p1;
                out[((size_t)(b * COUT + o) * 3 + 2) * NDIM + n] = p2;
            }
        }
    }
}

// ---------------------------------------------------------------------------
// FALLBACK PATH (ws too small): original verified kernels, unchanged.
// ---------------------------------------------------------------------------
__global__ __launch_bounds__(256) void vn_stats_mfma(
    const float* __restrict__ x, const unsigned short* __restrict__ wsu,
    float* __restrict__ stats)
{
    __shared__ unsigned short sXhi[192 * 40];
    __shared__ float redS[64], redQ[64];

    const int t  = threadIdx.x;
    const int n0 = blockIdx.x * 64;
    const int o0 = blockIdx.y * 64;
    const int b  = blockIdx.z;

    const int lane = t & 63;
    const int w    = t >> 6;
    const int q    = lane >> 4;
    const int ln   = lane & 15;

    const int jl = t & 31;
    const int kb = t >> 5;

    if (t < 64) { redS[t] = 0.f; redQ[t] = 0.f; }

    f32x4 acc[2][6];
    #pragma unroll
    for (int i = 0; i < 2; ++i)
        #pragma unroll
        for (int j = 0; j < 6; ++j) acc[i][j] = (f32x4)0.f;

    const unsigned short* wfh = wsu + WS_WFH;
    const int oo = o0 + (w >> 1) * 32;
    const int nb = (w & 1) * 32;

    for (int c0 = 0; c0 < CIN; c0 += 32) {
        __syncthreads();
        #pragma unroll
        for (int ip = 0; ip < 6; ++ip) {
            int jloc = ip * 32 + jl;
            int d = jloc >> 6, nl = jloc & 63;
            float v[4];
            #pragma unroll
            for (int i = 0; i < 4; ++i) {
                int c = c0 + kb + 8 * i;
                v[i] = x[((size_t)((b * CIN + c) * 3 + d)) * NDIM + n0 + nl];
            }
            unsigned p0 = (unsigned)f2bf(v[0]) | ((unsigned)f2bf(v[1]) << 16);
            unsigned p1 = (unsigned)f2bf(v[2]) | ((unsigned)f2bf(v[3]) << 16);
            *(uint2*)&sXhi[jloc * 40 + kb * 4] = make_uint2(p0, p1);
        }
        __syncthreads();
        bf16x8 af[2];
        #pragma unroll
        for (int mt = 0; mt < 2; ++mt)
            af[mt] = *(const bf16x8*)&wfh[(oo + mt * 16 + ln) * CIN + c0 + q * 8];
        #pragma unroll
        for (int nt = 0; nt < 6; ++nt) {
            int d = nt >> 1, h = nt & 1;
            int jloc = d * 64 + nb + h * 16 + ln;
            bf16x8 bh = *(const bf16x8*)&sXhi[jloc * 40 + q * 8];
            #pragma unroll
            for (int mt = 0; mt < 2; ++mt)
                acc[mt][nt] = __builtin_amdgcn_mfma_f32_16x16x32_bf16(af[mt], bh, acc[mt][nt], 0, 0, 0);
        }
    }

    #pragma unroll
    for (int mt = 0; mt < 2; ++mt) {
        #pragma unroll
        for (int r = 0; r < 4; ++r) {
            float s = 0.f, s2 = 0.f;
            #pragma unroll
            for (int h = 0; h < 2; ++h) {
                float p0 = acc[mt][0 + h][r];
                float p1 = acc[mt][2 + h][r];
                float p2 = acc[mt][4 + h][r];
                float n2 = p0 * p0 + p1 * p1 + p2 * p2;
                s += sqrtf(n2); s2 += n2;
            }
            #pragma unroll
            for (int m = 1; m < 16; m <<= 1) {
                s  += __shfl_xor(s,  m, 64);
                s2 += __shfl_xor(s2, m, 64);
            }
            if (ln == 0) {
                int ol = (w >> 1) * 32 + mt * 16 + q * 4 + r;
                atomicAdd(&redS[ol], s);
                atomicAdd(&redQ[ol], s2);
            }
        }
    }
    __syncthreads();
    if (t < 64) {
        int slot = blockIdx.x & (NSLOT - 1);
        atomicAdd(&stats[slot * 256 + o0 + t], redS[t]);
        atomicAdd(&stats[NSLOT * 256 + slot * 256 + o0 + t], redQ[t]);
    }
}

__global__ __launch_bounds__(256) void vn_main_mfma(
    const float* __restrict__ x, const unsigned short* __restrict__ wsu,
    const float* __restrict__ stats, const float* __restrict__ beta,
    float* __restrict__ out)
{
    __shared__ unsigned short sXhi[192 * 40];
    __shared__ unsigned short sXlo[192 * 40];

    const int t  = threadIdx.x;
    const int n0 = blockIdx.x * 64;
    const int o0 = blockIdx.y * 64;
    const int b  = blockIdx.z;

    const int lane = t & 63;
    const int w    = t >> 6;
    const int q    = lane >> 4;
    const int ln   = lane & 15;

    const int jl = t & 31;
    const int kb = t >> 5;

    f32x4 accP[2][6], accD[2][6];
    #pragma unroll
    for (int i = 0; i < 2; ++i)
        #pragma unroll
        for (int j = 0; j < 6; ++j) { accP[i][j] = (f32x4)0.f; accD[i][j] = (f32x4)0.f; }

    const unsigned short* wfh = wsu + WS_WFH;
    const unsigned short* wfl = wsu + WS_WFL;
    const unsigned short* wdh = wsu + WS_WDH;
    const unsigned short* wdl = wsu + WS_WDL;
    const int oo = o0 + (w >> 1) * 32;
    const int nb = (w & 1) * 32;

    for (int c0 = 0; c0 < CIN; c0 += 32) {
        __syncthreads();
        #pragma unroll
        for (int ip = 0; ip < 6; ++ip) {
            int jloc = ip * 32 + jl;
            int d = jloc >> 6, nl = jloc & 63;
            float v[4];
            #pragma unroll
            for (int i = 0; i < 4; ++i) {
                int c = c0 + kb + 8 * i;
                v[i] = x[((size_t)((b * CIN + c) * 3 + d)) * NDIM + n0 + nl];
            }
            unsigned short h0 = f2bf(v[0]), h1 = f2bf(v[1]), h2 = f2bf(v[2]), h3 = f2bf(v[3]);
            unsigned ph0 = (unsigned)h0 | ((unsigned)h1 << 16);
            unsigned ph1 = (unsigned)h2 | ((unsigned)h3 << 16);
            unsigned pl0 = (unsigned)f2bf(v[0] - bf2f(h0)) | ((unsigned)f2bf(v[1] - bf2f(h1)) << 16);
            unsigned pl1 = (unsigned)f2bf(v[2] - bf2f(h2)) | ((unsigned)f2bf(v[3] - bf2f(h3)) << 16);
            *(uint2*)&sXhi[jloc * 40 + kb * 4] = make_uint2(ph0, ph1);
            *(uint2*)&sXlo[jloc * 40 + kb * 4] = make_uint2(pl0, pl1);
        }
        __syncthreads();
        bf16x8 afh[2], afl[2], adh[2], adl[2];
        #pragma unroll
        for (int mt = 0; mt < 2; ++mt) {
            int row = (oo + mt * 16 + ln) * CIN + c0 + q * 8;
            afh[mt] = *(const bf16x8*)&wfh[row];
            afl[mt] = *(const bf16x8*)&wfl[row];
            adh[mt] = *(const bf16x8*)&wdh[row];
            adl[mt] = *(const bf16x8*)&wdl[row];
        }
        #pragma unroll
        for (int nt = 0; nt < 6; ++nt) {
            int d = nt >> 1, h = nt & 1;
            int jloc = d * 64 + nb + h * 16 + ln;
            bf16x8 bh = *(const bf16x8*)&sXhi[jloc * 40 + q * 8];
            bf16x8 bl = *(const bf16x8*)&sXlo[jloc * 40 + q * 8];
            #pragma unroll
            for (int mt = 0; mt < 2; ++mt) {
                f32x4 aP = accP[mt][nt];
                aP = __builtin_amdgcn_mfma_f32_16x16x32_bf16(afh[mt], bh, aP, 0, 0, 0);
                aP = __builtin_amdgcn_mfma_f32_16x16x32_bf16(afh[mt], bl, aP, 0, 0, 0);
                aP = __builtin_amdgcn_mfma_f32_16x16x32_bf16(afl[mt], bh, aP, 0, 0, 0);
                aP = __builtin_amdgcn_mfma_f32_16x16x32_bf16(afl[mt], bl, aP, 0, 0, 0);
                accP[mt][nt] = aP;
                f32x4 aD = accD[mt][nt];
                aD = __builtin_amdgcn_mfma_f32_16x16x32_bf16(adh[mt], bh, aD, 0, 0, 0);
                aD = __builtin_amdgcn_mfma_f32_16x16x32_bf16(adh[mt], bl, aD, 0, 0, 0);
                aD = __builtin_amdgcn_mfma_f32_16x16x32_bf16(adl[mt], bh, aD, 0, 0, 0);
                accD[mt][nt] = aD;
            }
        }
    }

    const float* meanp  = stats + 2 * NSLOT * 256;
    const float* scalep = meanp + 256;
    #pragma unroll
    for (int mt = 0; mt < 2; ++mt) {
        #pragma unroll
        for (int r = 0; r < 4; ++r) {
            const int o = oo + mt * 16 + q * 4 + r;
            const float mean  = meanp[o];
            const float scale = scalep[o];
            const float bet   = beta[o];
            #pragma unroll
            for (int h = 0; h < 2; ++h) {
                float p0 = accP[mt][0 + h][r], p1 = accP[mt][2 + h][r], p2 = accP[mt][4 + h][r];
                float d0 = accD[mt][0 + h][r], d1 = accD[mt][2 + h][r], d2 = accD[mt][4 + h][r];
                float n2 = p0 * p0 + p1 * p1 + p2 * p2;
                float nr = sqrtf(n2);
                float f  = ((nr - mean) * scale + bet) / nr;
                p0 *= f; p1 *= f; p2 *= f;
                float dot = p0 * d0 + p1 * d1 + p2 * d2;
                if (dot < 0.f) {
                    float g = NEG_COEF * dot / (d0 * d0 + d1 * d1 + d2 * d2 + LRELU_EPS);
                    p0 -= g * d0; p1 -= g * d1; p2 -= g * d2;
                }
                const int n = n0 + nb + h * 16 + ln;
                out[((size_t)(b * COUT + o) * 3 + 0) * NDIM + n] = p0;
                out[((size_t)(b * COUT + o) * 3 + 1) * NDIM + n] = p1;
                out[((size_t)(b * COUT + o) * 3 + 2) * NDIM + n] = p2;
            }
        }
    }
}

extern "C" void kernel_launch(void* const* d_in, const int* in_sizes, int n_in,
                              void* d_out, int out_size, void* d_ws, size_t ws_size,
                              hipStream_t stream) {
    const float* x     = (const float*)d_in[0];
    const float* Wf    = (const float*)d_in[1];
    const float* Wd    = (const float*)d_in[2];
    const float* gamma = (const float*)d_in[3];
    const float* beta  = (const float*)d_in[4];
    float* out = (float*)d_out;
    unsigned short* wsu = (unsigned short*)d_ws;
    float* stats = (float*)((char*)d_ws + WS_STATS_BYTE);

    hipMemsetAsync((char*)d_ws + WS_STATS_BYTE, 0, 2 * NSLOT * 256 * sizeof(float), stream);
    setup_w_kernel<<<dim3(256, 2), 256, 0, stream>>>(Wf, Wd, wsu);

    if (ws_size >= (size_t)WS_NEED) {
        char* xhp = (char*)d_ws + WS_XHI_BYTE;
        char* xlp = (char*)d_ws + WS_XLO_BYTE;
        vn_statscvt<<<dim3(128, 1, 8), 512, 0, stream>>>(x, wsu, xhp, xlp, stats);
        vn_finalize2<<<1, 256, 0, stream>>>(stats, gamma);
        vn_main2<<<dim3(128, 4, 8), 256, 0, stream>>>(wsu, xhp, xlp, stats, beta, out);
    } else {
        dim3 grid(NDIM / 64, COUT / 64, BDIM);
        vn_stats_mfma<<<grid, 256, 0, stream>>>(x, wsu, stats);
        vn_finalize2<<<1, 256, 0, stream>>>(stats, gamma);
        vn_main_mfma<<<grid, 256, 0, stream>>>(x, wsu, stats, beta, out);
    }
}

// Round 3
// 632.207 us; speedup vs baseline: 1.1204x; 1.1204x over previous
//
#include <hip/hip_runtime.h>
#include <math.h>

#define BDIM 8
#define CIN  256
#define COUT 256
#define NDIM 8192

#define NEG_COEF  0.8f
#define LRELU_EPS 1e-6f
#define BN_EPS    1e-5f

typedef __attribute__((ext_vector_type(8))) short bf16x8;   // 8 bf16 = 4 VGPRs
typedef __attribute__((ext_vector_type(4))) float f32x4;

// ws layout:
//   [0, 512KB)        : W fragments (hi/lo, feat/dir)
//   [512KB, +32K)     : BN stats scratch (floats)
//   [WS_XHI, +96MB)   : Xhi images, [b][nblk][ctile][12288B], swizzled LDS image
//   [WS_XLO, +96MB)   : Xlo images, same layout
#define WS_WFH 0
#define WS_WFL 65536
#define WS_WDH 131072
#define WS_WDL 196608
#define WS_STATS_BYTE 524288
#define NSLOT 8
#define TILE_BYTES 12288                         // 192 rows x 64 B (32 bf16)
#define WS_XHI_BYTE 557056
#define XIMG_BYTES 100663296ull                  // 8*128*8*12288
#define WS_XLO_BYTE (WS_XHI_BYTE + XIMG_BYTES)
#define WS_NEED (WS_XLO_BYTE + XIMG_BYTES)

__device__ __forceinline__ unsigned short f2bf(float f) {
    unsigned u = __float_as_uint(f);
    return (unsigned short)((u + 0x7FFFu + ((u >> 16) & 1u)) >> 16);
}
__device__ __forceinline__ float bf2f(unsigned short h) {
    return __uint_as_float(((unsigned)h) << 16);
}

// Bank swizzle for the X images: XOR bits 4-6 of the byte offset with (row&7),
// row = off>>6. Bijective; maps 16B chunks to 16B chunks; stays within each
// 128B-aligned block; makes the 16-lane stride-64B ds_read_b128 fragment
// reads conflict-free.
__device__ __forceinline__ int swz(int off) {
    return off ^ (((off >> 6) & 7) << 4);
}

__device__ __forceinline__ void gl_lds16(const char* g, char* l) {
    __builtin_amdgcn_global_load_lds(
        (const __attribute__((address_space(1))) unsigned int*)g,
        (__attribute__((address_space(3))) unsigned int*)l, 16, 0, 0);
}

// Convert W[o][c] fp32 -> bf16 hi/lo in fragment k-order (pos = 4*(c&7) + ((c>>3)&3)
// within each 32-k tile). Applied identically to A and B sides -> dot invariant.
__global__ __launch_bounds__(256) void setup_w_kernel(
    const float* __restrict__ Wf, const float* __restrict__ Wd,
    unsigned short* __restrict__ wsu)
{
    const int o = blockIdx.x;
    const int mat = blockIdx.y;
    const int c = threadIdx.x;
    const float* W = mat ? Wd : Wf;
    float w = W[o * CIN + c];
    unsigned short hi = f2bf(w);
    unsigned short lo = f2bf(w - bf2f(hi));
    int pos = (c & ~31) + 4 * (c & 7) + ((c >> 3) & 3);
    unsigned short* ph = wsu + (mat ? WS_WDH : WS_WFH);
    unsigned short* pl = wsu + (mat ? WS_WDL : WS_WFL);
    ph[o * CIN + pos] = hi;
    pl[o * CIN + pos] = lo;
}

// ---------------------------------------------------------------------------
// Kernel 1: pure streaming converter. Grid (128 nblk, 8 ct, 8 b), 256 thr.
// Each thread owns three LINEAR 16B chunks of the destination image and
// computes the swizzle-INVERSE to find its source (row, chunk): stores are
// lane-consecutive 16B (perfectly coalesced). No LDS, no barriers.
// ---------------------------------------------------------------------------
__global__ __launch_bounds__(256) void vn_convert(
    const float* __restrict__ x,
    char* __restrict__ xh, char* __restrict__ xl)
{
    const int t    = threadIdx.x;
    const int nblk = blockIdx.x;
    const int ct   = blockIdx.y;
    const int b    = blockIdx.z;
    const int n0   = nblk * 64;
    const int c0   = ct * 32;

    char* gh = xh + ((size_t)(b * 128 + nblk)) * (8 * TILE_BYTES) + ct * TILE_BYTES;
    char* gl = xl + ((size_t)(b * 128 + nblk)) * (8 * TILE_BYTES) + ct * TILE_BYTES;

    #pragma unroll
    for (int p = 0; p < 3; ++p) {
        const int m  = p * 256 + t;          // dest 16B-chunk index (linear)
        const int dr = m >> 2, dp = m & 3;   // dest row / chunk-in-row
        // inverse of swz: sr bit0 = dr bit0 ^ dr bit2; chunk = dp ^ (sr&3)
        const int sr = (dr & ~1) | ((dr ^ (dr >> 2)) & 1);
        const int sp = dp ^ (sr & 3);
        const int d  = sr >> 6, nl = sr & 63;
        const int kb = sp * 2;               // chunk holds kb and kb+1 sub-blocks
        float v[8];
        #pragma unroll
        for (int i = 0; i < 4; ++i) {
            const float* base = x + ((size_t)((b * CIN + c0 + kb + 8 * i) * 3 + d)) * NDIM + n0 + nl;
            v[i]     = base[0];              // c = c0+kb+8i
            v[4 + i] = base[3 * NDIM];       // c = c0+kb+1+8i
        }
        unsigned short h[8];
        #pragma unroll
        for (int j = 0; j < 8; ++j) h[j] = f2bf(v[j]);
        uint4 H = make_uint4((unsigned)h[0] | ((unsigned)h[1] << 16),
                             (unsigned)h[2] | ((unsigned)h[3] << 16),
                             (unsigned)h[4] | ((unsigned)h[5] << 16),
                             (unsigned)h[6] | ((unsigned)h[7] << 16));
        unsigned short lo[8];
        #pragma unroll
        for (int j = 0; j < 8; ++j) lo[j] = f2bf(v[j] - bf2f(h[j]));
        uint4 L = make_uint4((unsigned)lo[0] | ((unsigned)lo[1] << 16),
                             (unsigned)lo[2] | ((unsigned)lo[3] << 16),
                             (unsigned)lo[4] | ((unsigned)lo[5] << 16),
                             (unsigned)lo[6] | ((unsigned)lo[7] << 16));
        *(uint4*)(gh + m * 16) = H;
        *(uint4*)(gl + m * 16) = L;
    }
}

// ---------------------------------------------------------------------------
// Kernel 2: BN statistics from the hi image. Grid (128 nblk, 2 oy, 8 b),
// 256 thr, 4 waves x 32 o = 128 o per block. Double-buffered DMA pipeline
// with STATICALLY-NAMED buffers (no pointer arrays): STAGE(ct+1) issued
// before computing ct; __syncthreads() drains once per tile.
// ---------------------------------------------------------------------------
__device__ __forceinline__ void stats_step(
    int ct, const char* gh, const char* srd, char* swr,
    int t, int q, int ln, int oo,
    const unsigned short* wfh, f32x4 (*acc)[12])
{
    if (ct < 7) {                            // prefetch next tile (overlaps compute)
        #pragma unroll
        for (int p = 0; p < 3; ++p)
            gl_lds16(gh + (ct + 1) * TILE_BYTES + t * 16 + p * 4096,
                     swr + t * 16 + p * 4096);
    }
    bf16x8 af[2];
    #pragma unroll
    for (int mt = 0; mt < 2; ++mt)
        af[mt] = *(const bf16x8*)&wfh[(oo + mt * 16 + ln) * CIN + ct * 32 + q * 8];
    #pragma unroll
    for (int nt = 0; nt < 12; ++nt) {
        bf16x8 bh = *(const bf16x8*)(srd + swz((nt * 16 + ln) * 64 + q * 16));
        #pragma unroll
        for (int mt = 0; mt < 2; ++mt)
            acc[mt][nt] = __builtin_amdgcn_mfma_f32_16x16x32_bf16(af[mt], bh, acc[mt][nt], 0, 0, 0);
    }
    __syncthreads();                         // drain prefetch + finish reads
}

__global__ __launch_bounds__(256) void vn_stats2(
    const unsigned short* __restrict__ wsu, const char* __restrict__ xh,
    float* __restrict__ stats)
{
    __shared__ uint4 sA4[TILE_BYTES / 16];
    __shared__ uint4 sB4[TILE_BYTES / 16];
    __shared__ float redS[128], redQ[128];
    char* sA = (char*)sA4;
    char* sB = (char*)sB4;

    const int t    = threadIdx.x;
    const int nblk = blockIdx.x;
    const int oy   = blockIdx.y;
    const int b    = blockIdx.z;

    const int lane = t & 63;
    const int w    = t >> 6;
    const int q    = lane >> 4;
    const int ln   = lane & 15;
    const int oo   = oy * 128 + w * 32;

    if (t < 128) { redS[t] = 0.f; redQ[t] = 0.f; }

    f32x4 acc[2][12];
    #pragma unroll
    for (int i = 0; i < 2; ++i)
        #pragma unroll
        for (int j = 0; j < 12; ++j) acc[i][j] = (f32x4)0.f;

    const unsigned short* wfh = wsu + WS_WFH;
    const char* gh = xh + ((size_t)(b * 128 + nblk)) * (8 * TILE_BYTES);

    #pragma unroll
    for (int p = 0; p < 3; ++p)
        gl_lds16(gh + t * 16 + p * 4096, sA + t * 16 + p * 4096);
    __syncthreads();                          // drain prologue

    for (int cp = 0; cp < 4; ++cp) {
        stats_step(2 * cp,     gh, sA, sB, t, q, ln, oo, wfh, acc);
        stats_step(2 * cp + 1, gh, sB, sA, t, q, ln, oo, wfh, acc);
    }

    #pragma unroll
    for (int mt = 0; mt < 2; ++mt) {
        #pragma unroll
        for (int r = 0; r < 4; ++r) {
            float s = 0.f, s2 = 0.f;
            #pragma unroll
            for (int h = 0; h < 4; ++h) {
                float p0 = acc[mt][0 + h][r];
                float p1 = acc[mt][4 + h][r];
                float p2 = acc[mt][8 + h][r];
                float n2 = p0 * p0 + p1 * p1 + p2 * p2;
                s += sqrtf(n2); s2 += n2;
            }
            #pragma unroll
            for (int m = 1; m < 16; m <<= 1) {
                s  += __shfl_xor(s,  m, 64);
                s2 += __shfl_xor(s2, m, 64);
            }
            if (ln == 0) {
                int ol = w * 32 + mt * 16 + q * 4 + r;
                atomicAdd(&redS[ol], s);
                atomicAdd(&redQ[ol], s2);
            }
        }
    }
    __syncthreads();
    if (t < 128) {
        int slot = nblk & (NSLOT - 1);
        atomicAdd(&stats[slot * 256 + oy * 128 + t], redS[t]);
        atomicAdd(&stats[NSLOT * 256 + slot * 256 + oy * 128 + t], redQ[t]);
    }
}

__global__ __launch_bounds__(256) void vn_finalize2(
    float* __restrict__ stats, const float* __restrict__ gamma)
{
    int o = threadIdx.x;
    float s = 0.f, s2 = 0.f;
    #pragma unroll
    for (int i = 0; i < NSLOT; ++i) {
        s  += stats[i * 256 + o];
        s2 += stats[(NSLOT + i) * 256 + o];
    }
    const float inv = 1.0f / (float)(BDIM * NDIM);
    float mean = s * inv;
    float var  = fmaxf(s2 * inv - mean * mean, 0.f);
    stats[2 * NSLOT * 256 + o] = mean;
    stats[2 * NSLOT * 256 + 256 + o] = gamma[o] * rsqrtf(var + BN_EPS);
}

// ---------------------------------------------------------------------------
// Kernel 3: main GEMM + fused BN + VN-LeakyReLU. Grid (128, 4, 8), 256 thr.
// Double-buffered global_load_lds pipeline with statically-named buffers.
// ---------------------------------------------------------------------------
__device__ __forceinline__ void main_step(
    int ct, const char* ghb, const char* glb,
    const char* shr, const char* slr, char* shw, char* slw,
    int t, int q, int ln, int oo, int nb,
    const unsigned short* wfh, const unsigned short* wfl,
    const unsigned short* wdh, const unsigned short* wdl,
    f32x4 (*accP)[6], f32x4 (*accD)[6])
{
    if (ct < 7) {                            // prefetch next tile into write buffer
        #pragma unroll
        for (int p = 0; p < 3; ++p) {
            gl_lds16(ghb + (ct + 1) * TILE_BYTES + t * 16 + p * 4096,
                     shw + t * 16 + p * 4096);
            gl_lds16(glb + (ct + 1) * TILE_BYTES + t * 16 + p * 4096,
                     slw + t * 16 + p * 4096);
        }
    }
    const int c0 = ct * 32;
    bf16x8 afh[2], afl[2], adh[2], adl[2];
    #pragma unroll
    for (int mt = 0; mt < 2; ++mt) {
        const int row = (oo + mt * 16 + ln) * CIN + c0 + q * 8;
        afh[mt] = *(const bf16x8*)&wfh[row];
        afl[mt] = *(const bf16x8*)&wfl[row];
        adh[mt] = *(const bf16x8*)&wdh[row];
        adl[mt] = *(const bf16x8*)&wdl[row];
    }
    #pragma unroll
    for (int nt = 0; nt < 6; ++nt) {
        const int d = nt >> 1, h = nt & 1;
        const int jloc = d * 64 + nb + h * 16 + ln;
        const int off = swz(jloc * 64 + q * 16);
        bf16x8 bh = *(const bf16x8*)(shr + off);
        bf16x8 bl = *(const bf16x8*)(slr + off);
        #pragma unroll
        for (int mt = 0; mt < 2; ++mt) {
            f32x4 aP = accP[mt][nt];
            aP = __builtin_amdgcn_mfma_f32_16x16x32_bf16(afh[mt], bh, aP, 0, 0, 0);
            aP = __builtin_amdgcn_mfma_f32_16x16x32_bf16(afh[mt], bl, aP, 0, 0, 0);
            aP = __builtin_amdgcn_mfma_f32_16x16x32_bf16(afl[mt], bh, aP, 0, 0, 0);
            aP = __builtin_amdgcn_mfma_f32_16x16x32_bf16(afl[mt], bl, aP, 0, 0, 0);
            accP[mt][nt] = aP;
            f32x4 aD = accD[mt][nt];
            aD = __builtin_amdgcn_mfma_f32_16x16x32_bf16(adh[mt], bh, aD, 0, 0, 0);
            aD = __builtin_amdgcn_mfma_f32_16x16x32_bf16(adh[mt], bl, aD, 0, 0, 0);
            aD = __builtin_amdgcn_mfma_f32_16x16x32_bf16(adl[mt], bh, aD, 0, 0, 0);
            accD[mt][nt] = aD;
        }
    }
    __syncthreads();                         // drain prefetch + finish reads
}

__global__ __launch_bounds__(256) void vn_main3(
    const unsigned short* __restrict__ wsu,
    const char* __restrict__ xh, const char* __restrict__ xl,
    const float* __restrict__ stats, const float* __restrict__ beta,
    float* __restrict__ out)
{
    __shared__ uint4 sHA4[TILE_BYTES / 16];
    __shared__ uint4 sHB4[TILE_BYTES / 16];
    __shared__ uint4 sLA4[TILE_BYTES / 16];
    __shared__ uint4 sLB4[TILE_BYTES / 16];
    char* sHA = (char*)sHA4;
    char* sHB = (char*)sHB4;
    char* sLA = (char*)sLA4;
    char* sLB = (char*)sLB4;

    const int t    = threadIdx.x;
    const int nblk = blockIdx.x;
    const int n0   = nblk * 64;
    const int o0   = blockIdx.y * 64;
    const int b    = blockIdx.z;

    const int lane = t & 63;
    const int w    = t >> 6;
    const int q    = lane >> 4;
    const int ln   = lane & 15;

    f32x4 accP[2][6], accD[2][6];
    #pragma unroll
    for (int i = 0; i < 2; ++i)
        #pragma unroll
        for (int j = 0; j < 6; ++j) { accP[i][j] = (f32x4)0.f; accD[i][j] = (f32x4)0.f; }

    const unsigned short* wfh = wsu + WS_WFH;
    const unsigned short* wfl = wsu + WS_WFL;
    const unsigned short* wdh = wsu + WS_WDH;
    const unsigned short* wdl = wsu + WS_WDL;
    const int oo = o0 + (w >> 1) * 32;
    const int nb = (w & 1) * 32;

    const char* ghb = xh + ((size_t)(b * 128 + nblk)) * (8 * TILE_BYTES);
    const char* glb = xl + ((size_t)(b * 128 + nblk)) * (8 * TILE_BYTES);

    #pragma unroll
    for (int p = 0; p < 3; ++p) {
        gl_lds16(ghb + t * 16 + p * 4096, sHA + t * 16 + p * 4096);
        gl_lds16(glb + t * 16 + p * 4096, sLA + t * 16 + p * 4096);
    }
    __syncthreads();                          // drain prologue

    for (int cp = 0; cp < 4; ++cp) {
        main_step(2 * cp,     ghb, glb, sHA, sLA, sHB, sLB,
                  t, q, ln, oo, nb, wfh, wfl, wdh, wdl, accP, accD);
        main_step(2 * cp + 1, ghb, glb, sHB, sLB, sHA, sLA,
                  t, q, ln, oo, nb, wfh, wfl, wdh, wdl, accP, accD);
    }

    const float* meanp  = stats + 2 * NSLOT * 256;
    const float* scalep = meanp + 256;
    #pragma unroll
    for (int mt = 0; mt < 2; ++mt) {
        #pragma unroll
        for (int r = 0; r < 4; ++r) {
            const int o = oo + mt * 16 + q * 4 + r;
            const float mean  = meanp[o];
            const float scale = scalep[o];
            const float bet   = beta[o];
            #pragma unroll
            for (int h = 0; h < 2; ++h) {
                float p0 = accP[mt][0 + h][r], p1 = accP[mt][2 + h][r], p2 = accP[mt][4 + h][r];
                float d0 = accD[mt][0 + h][r], d1 = accD[mt][2 + h][r], d2 = accD[mt][4 + h][r];
                float n2 = p0 * p0 + p1 * p1 + p2 * p2;
                float nr = sqrtf(n2);
                float f  = ((nr - mean) * scale + bet) / nr;
                p0 *= f; p1 *= f; p2 *= f;
                float dot = p0 * d0 + p1 * d1 + p2 * d2;
                if (dot < 0.f) {
                    float g = NEG_COEF * dot / (d0 * d0 + d1 * d1 + d2 * d2 + LRELU_EPS);
                    p0 -= g * d0; p1 -= g * d1; p2 -= g * d2;
                }
                const int n = n0 + nb + h * 16 + ln;
                out[((size_t)(b * COUT + o) * 3 + 0) * NDIM + n] = p0;
                out[((size_t)(b * COUT + o) * 3 + 1) * NDIM + n] = p1;
                out[((size_t)(b * COUT + o) * 3 + 2) * NDIM + n] = p2;
            }
        }
    }
}

// ---------------------------------------------------------------------------
// FALLBACK PATH (ws too small): original verified kernels, unchanged.
// ---------------------------------------------------------------------------
__global__ __launch_bounds__(256) void vn_stats_mfma(
    const float* __restrict__ x, const unsigned short* __restrict__ wsu,
    float* __restrict__ stats)
{
    __shared__ unsigned short sXhi[192 * 40];
    __shared__ float redS[64], redQ[64];

    const int t  = threadIdx.x;
    const int n0 = blockIdx.x * 64;
    const int o0 = blockIdx.y * 64;
    const int b  = blockIdx.z;

    const int lane = t & 63;
    const int w    = t >> 6;
    const int q    = lane >> 4;
    const int ln   = lane & 15;

    const int jl = t & 31;
    const int kb = t >> 5;

    if (t < 64) { redS[t] = 0.f; redQ[t] = 0.f; }

    f32x4 acc[2][6];
    #pragma unroll
    for (int i = 0; i < 2; ++i)
        #pragma unroll
        for (int j = 0; j < 6; ++j) acc[i][j] = (f32x4)0.f;

    const unsigned short* wfh = wsu + WS_WFH;
    const int oo = o0 + (w >> 1) * 32;
    const int nb = (w & 1) * 32;

    for (int c0 = 0; c0 < CIN; c0 += 32) {
        __syncthreads();
        #pragma unroll
        for (int ip = 0; ip < 6; ++ip) {
            int jloc = ip * 32 + jl;
            int d = jloc >> 6, nl = jloc & 63;
            float v[4];
            #pragma unroll
            for (int i = 0; i < 4; ++i) {
                int c = c0 + kb + 8 * i;
                v[i] = x[((size_t)((b * CIN + c) * 3 + d)) * NDIM + n0 + nl];
            }
            unsigned p0 = (unsigned)f2bf(v[0]) | ((unsigned)f2bf(v[1]) << 16);
            unsigned p1 = (unsigned)f2bf(v[2]) | ((unsigned)f2bf(v[3]) << 16);
            *(uint2*)&sXhi[jloc * 40 + kb * 4] = make_uint2(p0, p1);
        }
        __syncthreads();
        bf16x8 af[2];
        #pragma unroll
        for (int mt = 0; mt < 2; ++mt)
            af[mt] = *(const bf16x8*)&wfh[(oo + mt * 16 + ln) * CIN + c0 + q * 8];
        #pragma unroll
        for (int nt = 0; nt < 6; ++nt) {
            int d = nt >> 1, h = nt & 1;
            int jloc = d * 64 + nb + h * 16 + ln;
            bf16x8 bh = *(const bf16x8*)&sXhi[jloc * 40 + q * 8];
            #pragma unroll
            for (int mt = 0; mt < 2; ++mt)
                acc[mt][nt] = __builtin_amdgcn_mfma_f32_16x16x32_bf16(af[mt], bh, acc[mt][nt], 0, 0, 0);
        }
    }

    #pragma unroll
    for (int mt = 0; mt < 2; ++mt) {
        #pragma unroll
        for (int r = 0; r < 4; ++r) {
            float s = 0.f, s2 = 0.f;
            #pragma unroll
            for (int h = 0; h < 2; ++h) {
                float p0 = acc[mt][0 + h][r];
                float p1 = acc[mt][2 + h][r];
                float p2 = acc[mt][4 + h][r];
                float n2 = p0 * p0 + p1 * p1 + p2 * p2;
                s += sqrtf(n2); s2 += n2;
            }
            #pragma unroll
            for (int m = 1; m < 16; m <<= 1) {
                s  += __shfl_xor(s,  m, 64);
                s2 += __shfl_xor(s2, m, 64);
            }
            if (ln == 0) {
                int ol = (w >> 1) * 32 + mt * 16 + q * 4 + r;
                atomicAdd(&redS[ol], s);
                atomicAdd(&redQ[ol], s2);
            }
        }
    }
    __syncthreads();
    if (t < 64) {
        int slot = blockIdx.x & (NSLOT - 1);
        atomicAdd(&stats[slot * 256 + o0 + t], redS[t]);
        atomicAdd(&stats[NSLOT * 256 + slot * 256 + o0 + t], redQ[t]);
    }
}

__global__ __launch_bounds__(256) void vn_main_mfma(
    const float* __restrict__ x, const unsigned short* __restrict__ wsu,
    const float* __restrict__ stats, const float* __restrict__ beta,
    float* __restrict__ out)
{
    __shared__ unsigned short sXhi[192 * 40];
    __shared__ unsigned short sXlo[192 * 40];

    const int t  = threadIdx.x;
    const int n0 = blockIdx.x * 64;
    const int o0 = blockIdx.y * 64;
    const int b  = blockIdx.z;

    const int lane = t & 63;
    const int w    = t >> 6;
    const int q    = lane >> 4;
    const int ln   = lane & 15;

    const int jl = t & 31;
    const int kb = t >> 5;

    f32x4 accP[2][6], accD[2][6];
    #pragma unroll
    for (int i = 0; i < 2; ++i)
        #pragma unroll
        for (int j = 0; j < 6; ++j) { accP[i][j] = (f32x4)0.f; accD[i][j] = (f32x4)0.f; }

    const unsigned short* wfh = wsu + WS_WFH;
    const unsigned short* wfl = wsu + WS_WFL;
    const unsigned short* wdh = wsu + WS_WDH;
    const unsigned short* wdl = wsu + WS_WDL;
    const int oo = o0 + (w >> 1) * 32;
    const int nb = (w & 1) * 32;

    for (int c0 = 0; c0 < CIN; c0 += 32) {
        __syncthreads();
        #pragma unroll
        for (int ip = 0; ip < 6; ++ip) {
            int jloc = ip * 32 + jl;
            int d = jloc >> 6, nl = jloc & 63;
            float v[4];
            #pragma unroll
            for (int i = 0; i < 4; ++i) {
                int c = c0 + kb + 8 * i;
                v[i] = x[((size_t)((b * CIN + c) * 3 + d)) * NDIM + n0 + nl];
            }
            unsigned short h0 = f2bf(v[0]), h1 = f2bf(v[1]), h2 = f2bf(v[2]), h3 = f2bf(v[3]);
            unsigned ph0 = (unsigned)h0 | ((unsigned)h1 << 16);
            unsigned ph1 = (unsigned)h2 | ((unsigned)h3 << 16);
            unsigned pl0 = (unsigned)f2bf(v[0] - bf2f(h0)) | ((unsigned)f2bf(v[1] - bf2f(h1)) << 16);
            unsigned pl1 = (unsigned)f2bf(v[2] - bf2f(h2)) | ((unsigned)f2bf(v[3] - bf2f(h3)) << 16);
            *(uint2*)&sXhi[jloc * 40 + kb * 4] = make_uint2(ph0, ph1);
            *(uint2*)&sXlo[jloc * 40 + kb * 4] = make_uint2(pl0, pl1);
        }
        __syncthreads();
        bf16x8 afh[2], afl[2], adh[2], adl[2];
        #pragma unroll
        for (int mt = 0; mt < 2; ++mt) {
            int row = (oo + mt * 16 + ln) * CIN + c0 + q * 8;
            afh[mt] = *(const bf16x8*)&wfh[row];
            afl[mt] = *(const bf16x8*)&wfl[row];
            adh[mt] = *(const bf16x8*)&wdh[row];
            adl[mt] = *(const bf16x8*)&wdl[row];
        }
        #pragma unroll
        for (int nt = 0; nt < 6; ++nt) {
            int d = nt >> 1, h = nt & 1;
            int jloc = d * 64 + nb + h * 16 + ln;
            bf16x8 bh = *(const bf16x8*)&sXhi[jloc * 40 + q * 8];
            bf16x8 bl = *(const bf16x8*)&sXlo[jloc * 40 + q * 8];
            #pragma unroll
            for (int mt = 0; mt < 2; ++mt) {
                f32x4 aP = accP[mt][nt];
                aP = __builtin_amdgcn_mfma_f32_16x16x32_bf16(afh[mt], bh, aP, 0, 0, 0);
                aP = __builtin_amdgcn_mfma_f32_16x16x32_bf16(afh[mt], bl, aP, 0, 0, 0);
                aP = __builtin_amdgcn_mfma_f32_16x16x32_bf16(afl[mt], bh, aP, 0, 0, 0);
                aP = __builtin_amdgcn_mfma_f32_16x16x32_bf16(afl[mt], bl, aP, 0, 0, 0);
                accP[mt][nt] = aP;
                f32x4 aD = accD[mt][nt];
                aD = __builtin_amdgcn_mfma_f32_16x16x32_bf16(adh[mt], bh, aD, 0, 0, 0);
                aD = __builtin_amdgcn_mfma_f32_16x16x32_bf16(adh[mt], bl, aD, 0, 0, 0);
                aD = __builtin_amdgcn_mfma_f32_16x16x32_bf16(adl[mt], bh, aD, 0, 0, 0);
                accD[mt][nt] = aD;
            }
        }
    }

    const float* meanp  = stats + 2 * NSLOT * 256;
    const float* scalep = meanp + 256;
    #pragma unroll
    for (int mt = 0; mt < 2; ++mt) {
        #pragma unroll
        for (int r = 0; r < 4; ++r) {
            const int o = oo + mt * 16 + q * 4 + r;
            const float mean  = meanp[o];
            const float scale = scalep[o];
            const float bet   = beta[o];
            #pragma unroll
            for (int h = 0; h < 2; ++h) {
                float p0 = accP[mt][0 + h][r], p1 = accP[mt][2 + h][r], p2 = accP[mt][4 + h][r];
                float d0 = accD[mt][0 + h][r], d1 = accD[mt][2 + h][r], d2 = accD[mt][4 + h][r];
                float n2 = p0 * p0 + p1 * p1 + p2 * p2;
                float nr = sqrtf(n2);
                float f  = ((nr - mean) * scale + bet) / nr;
                p0 *= f; p1 *= f; p2 *= f;
                float dot = p0 * d0 + p1 * d1 + p2 * d2;
                if (dot < 0.f) {
                    float g = NEG_COEF * dot / (d0 * d0 + d1 * d1 + d2 * d2 + LRELU_EPS);
                    p0 -= g * d0; p1 -= g * d1; p2 -= g * d2;
                }
                const int n = n0 + nb + h * 16 + ln;
                out[((size_t)(b * COUT + o) * 3 + 0) * NDIM + n] = p0;
                out[((size_t)(b * COUT + o) * 3 + 1) * NDIM + n] = p1;
                out[((size_t)(b * COUT + o) * 3 + 2) * NDIM + n] = p2;
            }
        }
    }
}

extern "C" void kernel_launch(void* const* d_in, const int* in_sizes, int n_in,
                              void* d_out, int out_size, void* d_ws, size_t ws_size,
                              hipStream_t stream) {
    const float* x     = (const float*)d_in[0];
    const float* Wf    = (const float*)d_in[1];
    const float* Wd    = (const float*)d_in[2];
    const float* gamma = (const float*)d_in[3];
    const float* beta  = (const float*)d_in[4];
    float* out = (float*)d_out;
    unsigned short* wsu = (unsigned short*)d_ws;
    float* stats = (float*)((char*)d_ws + WS_STATS_BYTE);

    hipMemsetAsync((char*)d_ws + WS_STATS_BYTE, 0, 2 * NSLOT * 256 * sizeof(float), stream);
    setup_w_kernel<<<dim3(256, 2), 256, 0, stream>>>(Wf, Wd, wsu);

    if (ws_size >= (size_t)WS_NEED) {
        char* xhp = (char*)d_ws + WS_XHI_BYTE;
        char* xlp = (char*)d_ws + WS_XLO_BYTE;
        vn_convert<<<dim3(128, 8, 8), 256, 0, stream>>>(x, xhp, xlp);
        vn_stats2<<<dim3(128, 2, 8), 256, 0, stream>>>(wsu, xhp, stats);
        vn_finalize2<<<1, 256, 0, stream>>>(stats, gamma);
        vn_main3<<<dim3(128, 4, 8), 256, 0, stream>>>(wsu, xhp, xlp, stats, beta, out);
    } else {
        dim3 grid(NDIM / 64, COUT / 64, BDIM);
        vn_stats_mfma<<<grid, 256, 0, stream>>>(x, wsu, stats);
        vn_finalize2<<<1, 256, 0, stream>>>(stats, gamma);
        vn_main_mfma<<<grid, 256, 0, stream>>>(x, wsu, stats, beta, out);
    }
}

// Round 4
// 612.782 us; speedup vs baseline: 1.1560x; 1.0317x over previous
//
#include <hip/hip_runtime.h>
#include <math.h>

#define BDIM 8
#define CIN  256
#define COUT 256
#define NDIM 8192

#define NEG_COEF  0.8f
#define LRELU_EPS 1e-6f
#define BN_EPS    1e-5f

typedef __attribute__((ext_vector_type(8))) short bf16x8;   // 8 bf16 = 4 VGPRs
typedef __attribute__((ext_vector_type(4))) float f32x4;

// ws layout:
//   [0, 512KB)        : W fragments (hi/lo, feat/dir)
//   [512KB, +32K)     : BN stats scratch (floats)
//   [WS_XHI, +96MB)   : Xhi images, [b][nblk][ctile][12288B], swizzled LDS image
//   [WS_XLO, +96MB)   : Xlo images, same layout
#define WS_WFH 0
#define WS_WFL 65536
#define WS_WDH 131072
#define WS_WDL 196608
#define WS_STATS_BYTE 524288
#define NSLOT 8
#define TILE_BYTES 12288                         // 192 rows x 64 B (32 bf16)
#define WS_XHI_BYTE 557056
#define XIMG_BYTES 100663296ull                  // 8*128*8*12288
#define WS_XLO_BYTE (WS_XHI_BYTE + XIMG_BYTES)
#define WS_NEED (WS_XLO_BYTE + XIMG_BYTES)

#define XT_PITCH 68                              // x-tile row pitch in floats (64+4 pad)

__device__ __forceinline__ unsigned short f2bf(float f) {
    unsigned u = __float_as_uint(f);
    return (unsigned short)((u + 0x7FFFu + ((u >> 16) & 1u)) >> 16);
}
__device__ __forceinline__ float bf2f(unsigned short h) {
    return __uint_as_float(((unsigned)h) << 16);
}

// Bank swizzle for the X images: byte bits 4-6 ^= bits 6-8 (row low bits).
// Bijective (each target bit XORs a strictly higher bit); maps 16B chunks
// to 16B chunks; makes the 16-lane stride-64B ds_read_b128 fragment reads
// conflict-free. Verified on HW (R1/R3 passed).
__device__ __forceinline__ int swz(int off) {
    return off ^ (((off >> 6) & 7) << 4);
}

__device__ __forceinline__ void gl_lds16(const char* g, char* l) {
    __builtin_amdgcn_global_load_lds(
        (const __attribute__((address_space(1))) unsigned int*)g,
        (__attribute__((address_space(3))) unsigned int*)l, 16, 0, 0);
}

// Convert W[o][c] fp32 -> bf16 hi/lo in fragment k-order (pos = 4*(c&7) + ((c>>3)&3)
// within each 32-k tile). Applied identically to A and B sides -> dot invariant.
__global__ __launch_bounds__(256) void setup_w_kernel(
    const float* __restrict__ Wf, const float* __restrict__ Wd,
    unsigned short* __restrict__ wsu)
{
    const int o = blockIdx.x;
    const int mat = blockIdx.y;
    const int c = threadIdx.x;
    const float* W = mat ? Wd : Wf;
    float w = W[o * CIN + c];
    unsigned short hi = f2bf(w);
    unsigned short lo = f2bf(w - bf2f(hi));
    int pos = (c & ~31) + 4 * (c & 7) + ((c >> 3) & 3);
    unsigned short* ph = wsu + (mat ? WS_WDH : WS_WFH);
    unsigned short* pl = wsu + (mat ? WS_WDL : WS_WFL);
    ph[o * CIN + pos] = hi;
    pl[o * CIN + pos] = lo;
}

// Build one 16B dest chunk m (and its lo twin): gather 8 floats from the LDS
// x-tile via the inverse swizzle (same mapping as R3's verified vn_convert,
// sources moved from global to LDS), convert to bf16 hi/lo, write hi chunk to
// the LDS image (linear dest = image layout) + both chunks to global.
__device__ __forceinline__ void build_chunk(
    int m, const float* __restrict__ xs, char* __restrict__ img,
    char* __restrict__ gh, char* __restrict__ gl)
{
    const int dr = m >> 2, dp = m & 3;
    // inverse of swz (verified): sr bit0 = dr bit0 ^ dr bit2; sp = dp ^ (sr&3)
    const int sr = (dr & ~1) | ((dr ^ (dr >> 2)) & 1);
    const int sp = dp ^ (sr & 3);
    const int d  = sr >> 6, nl = sr & 63;
    const int kb = sp * 2;
    float v[8];
    #pragma unroll
    for (int i = 0; i < 4; ++i) {
        v[i]     = xs[((kb + 8 * i) * 3 + d) * XT_PITCH + nl];
        v[4 + i] = xs[((kb + 1 + 8 * i) * 3 + d) * XT_PITCH + nl];
    }
    unsigned short h[8];
    #pragma unroll
    for (int j = 0; j < 8; ++j) h[j] = f2bf(v[j]);
    uint4 H = make_uint4((unsigned)h[0] | ((unsigned)h[1] << 16),
                         (unsigned)h[2] | ((unsigned)h[3] << 16),
                         (unsigned)h[4] | ((unsigned)h[5] << 16),
                         (unsigned)h[6] | ((unsigned)h[7] << 16));
    unsigned short lo[8];
    #pragma unroll
    for (int j = 0; j < 8; ++j) lo[j] = f2bf(v[j] - bf2f(h[j]));
    uint4 L = make_uint4((unsigned)lo[0] | ((unsigned)lo[1] << 16),
                         (unsigned)lo[2] | ((unsigned)lo[3] << 16),
                         (unsigned)lo[4] | ((unsigned)lo[5] << 16),
                         (unsigned)lo[6] | ((unsigned)lo[7] << 16));
    *(uint4*)(img + m * 16) = H;
    *(uint4*)(gh + m * 16)  = H;
    *(uint4*)(gl + m * 16)  = L;
}

// ---------------------------------------------------------------------------
// Fused convert + stats. Grid (128 nblk, 1, 8 b), 512 threads (8 waves).
// Reads x ONCE (coalesced float4), writes both images ONCE, computes the
// hi-product BN statistics for all 256 channels from the LDS image it just
// built. Per c-tile: A(x regs->LDS) |bar| B(build+stores) |bar| C(next
// loads->regs; MFMA). All LDS hazards cross a barrier; regs carry loads.
// ---------------------------------------------------------------------------
__global__ __launch_bounds__(512) void vn_cvtstats(
    const float* __restrict__ x, const unsigned short* __restrict__ wsu,
    char* __restrict__ xh, char* __restrict__ xl,
    float* __restrict__ stats)
{
    __shared__ float xs[96 * XT_PITCH];          // 25.5 KB fp32 x-tile
    __shared__ uint4 img4[TILE_BYTES / 16];      // 12 KB hi image tile
    __shared__ float redS[256], redQ[256];
    char* img = (char*)img4;

    const int t    = threadIdx.x;                // 0..511
    const int nblk = blockIdx.x;
    const int b    = blockIdx.z;
    const int n0   = nblk * 64;

    const int lane = t & 63;
    const int w    = t >> 6;                     // 0..7
    const int q    = lane >> 4;
    const int ln   = lane & 15;
    const int oo   = w * 32;

    if (t < 256) { redS[t] = 0.f; redQ[t] = 0.f; }

    f32x4 acc[2][12];
    #pragma unroll
    for (int i = 0; i < 2; ++i)
        #pragma unroll
        for (int j = 0; j < 12; ++j) acc[i][j] = (f32x4)0.f;

    const unsigned short* wfh = wsu + WS_WFH;
    char* ghb = xh + ((size_t)(b * 128 + nblk)) * (8 * TILE_BYTES);
    char* glb = xl + ((size_t)(b * 128 + nblk)) * (8 * TILE_BYTES);
    // x-tile rows (c_local*3 + d) are consecutive NDIM-strided rows from here:
    const float* xb0 = x + ((size_t)(b * CIN) * 3) * NDIM + n0;

    float4 xr[3];
    #pragma unroll
    for (int k = 0; k < 3; ++k) {                // prologue: tile 0 -> regs
        const int idx = k * 512 + t;             // 0..1535 float4 chunks
        const int row = idx >> 4, col = idx & 15;
        xr[k] = *(const float4*)(xb0 + (size_t)row * NDIM + col * 4);
    }

    for (int ct = 0; ct < 8; ++ct) {
        __syncthreads();      // prev B's xs reads + prev C's img reads done
        #pragma unroll
        for (int k = 0; k < 3; ++k) {            // A: regs -> xs
            const int idx = k * 512 + t;
            const int row = idx >> 4, col = idx & 15;
            *(float4*)&xs[row * XT_PITCH + col * 4] = xr[k];
        }
        __syncthreads();      // xs ready
        // B: build 768 chunks (thread t: m=t; t<256 also m=512+t)
        build_chunk(t, xs, img, ghb + ct * TILE_BYTES, glb + ct * TILE_BYTES);
        if (t < 256)
            build_chunk(512 + t, xs, img, ghb + ct * TILE_BYTES, glb + ct * TILE_BYTES);
        __syncthreads();      // img ready (xs fully consumed)
        // C: issue next tile's loads early (hidden under MFMA), then MFMA
        if (ct < 7) {
            const float* xbn = xb0 + (size_t)(ct + 1) * 32 * 3 * NDIM;
            #pragma unroll
            for (int k = 0; k < 3; ++k) {
                const int idx = k * 512 + t;
                const int row = idx >> 4, col = idx & 15;
                xr[k] = *(const float4*)(xbn + (size_t)row * NDIM + col * 4);
            }
        }
        bf16x8 af[2];
        #pragma unroll
        for (int mt = 0; mt < 2; ++mt)
            af[mt] = *(const bf16x8*)&wfh[(oo + mt * 16 + ln) * CIN + ct * 32 + q * 8];
        #pragma unroll
        for (int nt = 0; nt < 12; ++nt) {
            bf16x8 bh = *(const bf16x8*)(img + swz((nt * 16 + ln) * 64 + q * 16));
            #pragma unroll
            for (int mt = 0; mt < 2; ++mt)
                acc[mt][nt] = __builtin_amdgcn_mfma_f32_16x16x32_bf16(af[mt], bh, acc[mt][nt], 0, 0, 0);
        }
    }

    // stats epilogue (verified R1 structure): nt = d*4 + h
    #pragma unroll
    for (int mt = 0; mt < 2; ++mt) {
        #pragma unroll
        for (int r = 0; r < 4; ++r) {
            float s = 0.f, s2 = 0.f;
            #pragma unroll
            for (int h = 0; h < 4; ++h) {
                float p0 = acc[mt][0 + h][r];
                float p1 = acc[mt][4 + h][r];
                float p2 = acc[mt][8 + h][r];
                float n2 = p0 * p0 + p1 * p1 + p2 * p2;
                s += sqrtf(n2); s2 += n2;
            }
            #pragma unroll
            for (int m = 1; m < 16; m <<= 1) {
                s  += __shfl_xor(s,  m, 64);
                s2 += __shfl_xor(s2, m, 64);
            }
            if (ln == 0) {
                int o = oo + mt * 16 + q * 4 + r;
                atomicAdd(&redS[o], s);
                atomicAdd(&redQ[o], s2);
            }
        }
    }
    __syncthreads();
    if (t < 256) {
        int slot = nblk & (NSLOT - 1);
        atomicAdd(&stats[slot * 256 + t], redS[t]);
        atomicAdd(&stats[NSLOT * 256 + slot * 256 + t], redQ[t]);
    }
}

__global__ __launch_bounds__(256) void vn_finalize2(
    float* __restrict__ stats, const float* __restrict__ gamma)
{
    int o = threadIdx.x;
    float s = 0.f, s2 = 0.f;
    #pragma unroll
    for (int i = 0; i < NSLOT; ++i) {
        s  += stats[i * 256 + o];
        s2 += stats[(NSLOT + i) * 256 + o];
    }
    const float inv = 1.0f / (float)(BDIM * NDIM);
    float mean = s * inv;
    float var  = fmaxf(s2 * inv - mean * mean, 0.f);
    stats[2 * NSLOT * 256 + o] = mean;
    stats[2 * NSLOT * 256 + 256 + o] = gamma[o] * rsqrtf(var + BN_EPS);
}

// ---------------------------------------------------------------------------
// Main GEMM + fused BN + VN-LeakyReLU. Grid (128, 4, 8), 256 thr.
// Double-buffered global_load_lds pipeline with statically-named buffers.
// (Unchanged from R3 — verified at 255 µs.)
// ---------------------------------------------------------------------------
__device__ __forceinline__ void main_step(
    int ct, const char* ghb, const char* glb,
    const char* shr, const char* slr, char* shw, char* slw,
    int t, int q, int ln, int oo, int nb,
    const unsigned short* wfh, const unsigned short* wfl,
    const unsigned short* wdh, const unsigned short* wdl,
    f32x4 (*accP)[6], f32x4 (*accD)[6])
{
    if (ct < 7) {                            // prefetch next tile into write buffer
        #pragma unroll
        for (int p = 0; p < 3; ++p) {
            gl_lds16(ghb + (ct + 1) * TILE_BYTES + t * 16 + p * 4096,
                     shw + t * 16 + p * 4096);
            gl_lds16(glb + (ct + 1) * TILE_BYTES + t * 16 + p * 4096,
                     slw + t * 16 + p * 4096);
        }
    }
    const int c0 = ct * 32;
    bf16x8 afh[2], afl[2], adh[2], adl[2];
    #pragma unroll
    for (int mt = 0; mt < 2; ++mt) {
        const int row = (oo + mt * 16 + ln) * CIN + c0 + q * 8;
        afh[mt] = *(const bf16x8*)&wfh[row];
        afl[mt] = *(const bf16x8*)&wfl[row];
        adh[mt] = *(const bf16x8*)&wdh[row];
        adl[mt] = *(const bf16x8*)&wdl[row];
    }
    #pragma unroll
    for (int nt = 0; nt < 6; ++nt) {
        const int d = nt >> 1, h = nt & 1;
        const int jloc = d * 64 + nb + h * 16 + ln;
        const int off = swz(jloc * 64 + q * 16);
        bf16x8 bh = *(const bf16x8*)(shr + off);
        bf16x8 bl = *(const bf16x8*)(slr + off);
        #pragma unroll
        for (int mt = 0; mt < 2; ++mt) {
            f32x4 aP = accP[mt][nt];
            aP = __builtin_amdgcn_mfma_f32_16x16x32_bf16(afh[mt], bh, aP, 0, 0, 0);
            aP = __builtin_amdgcn_mfma_f32_16x16x32_bf16(afh[mt], bl, aP, 0, 0, 0);
            aP = __builtin_amdgcn_mfma_f32_16x16x32_bf16(afl[mt], bh, aP, 0, 0, 0);
            aP = __builtin_amdgcn_mfma_f32_16x16x32_bf16(afl[mt], bl, aP, 0, 0, 0);
            accP[mt][nt] = aP;
            f32x4 aD = accD[mt][nt];
            aD = __builtin_amdgcn_mfma_f32_16x16x32_bf16(adh[mt], bh, aD, 0, 0, 0);
            aD = __builtin_amdgcn_mfma_f32_16x16x32_bf16(adh[mt], bl, aD, 0, 0, 0);
            aD = __builtin_amdgcn_mfma_f32_16x16x32_bf16(adl[mt], bh, aD, 0, 0, 0);
            accD[mt][nt] = aD;
        }
    }
    __syncthreads();                         // drain prefetch + finish reads
}

__global__ __launch_bounds__(256) void vn_main3(
    const unsigned short* __restrict__ wsu,
    const char* __restrict__ xh, const char* __restrict__ xl,
    const float* __restrict__ stats, const float* __restrict__ beta,
    float* __restrict__ out)
{
    __shared__ uint4 sHA4[TILE_BYTES / 16];
    __shared__ uint4 sHB4[TILE_BYTES / 16];
    __shared__ uint4 sLA4[TILE_BYTES / 16];
    __shared__ uint4 sLB4[TILE_BYTES / 16];
    char* sHA = (char*)sHA4;
    char* sHB = (char*)sHB4;
    char* sLA = (char*)sLA4;
    char* sLB = (char*)sLB4;

    const int t    = threadIdx.x;
    const int nblk = blockIdx.x;
    const int n0   = nblk * 64;
    const int o0   = blockIdx.y * 64;
    const int b    = blockIdx.z;

    const int lane = t & 63;
    const int w    = t >> 6;
    const int q    = lane >> 4;
    const int ln   = lane & 15;

    f32x4 accP[2][6], accD[2][6];
    #pragma unroll
    for (int i = 0; i < 2; ++i)
        #pragma unroll
        for (int j = 0; j < 6; ++j) { accP[i][j] = (f32x4)0.f; accD[i][j] = (f32x4)0.f; }

    const unsigned short* wfh = wsu + WS_WFH;
    const unsigned short* wfl = wsu + WS_WFL;
    const unsigned short* wdh = wsu + WS_WDH;
    const unsigned short* wdl = wsu + WS_WDL;
    const int oo = o0 + (w >> 1) * 32;
    const int nb = (w & 1) * 32;

    const char* ghb = xh + ((size_t)(b * 128 + nblk)) * (8 * TILE_BYTES);
    const char* glb = xl + ((size_t)(b * 128 + nblk)) * (8 * TILE_BYTES);

    #pragma unroll
    for (int p = 0; p < 3; ++p) {
        gl_lds16(ghb + t * 16 + p * 4096, sHA + t * 16 + p * 4096);
        gl_lds16(glb + t * 16 + p * 4096, sLA + t * 16 + p * 4096);
    }
    __syncthreads();                          // drain prologue

    for (int cp = 0; cp < 4; ++cp) {
        main_step(2 * cp,     ghb, glb, sHA, sLA, sHB, sLB,
                  t, q, ln, oo, nb, wfh, wfl, wdh, wdl, accP, accD);
        main_step(2 * cp + 1, ghb, glb, sHB, sLB, sHA, sLA,
                  t, q, ln, oo, nb, wfh, wfl, wdh, wdl, accP, accD);
    }

    const float* meanp  = stats + 2 * NSLOT * 256;
    const float* scalep = meanp + 256;
    #pragma unroll
    for (int mt = 0; mt < 2; ++mt) {
        #pragma unroll
        for (int r = 0; r < 4; ++r) {
            const int o = oo + mt * 16 + q * 4 + r;
            const float mean  = meanp[o];
            const float scale = scalep[o];
            const float bet   = beta[o];
            #pragma unroll
            for (int h = 0; h < 2; ++h) {
                float p0 = accP[mt][0 + h][r], p1 = accP[mt][2 + h][r], p2 = accP[mt][4 + h][r];
                float d0 = accD[mt][0 + h][r], d1 = accD[mt][2 + h][r], d2 = accD[mt][4 + h][r];
                float n2 = p0 * p0 + p1 * p1 + p2 * p2;
                float nr = sqrtf(n2);
                float f  = ((nr - mean) * scale + bet) / nr;
                p0 *= f; p1 *= f; p2 *= f;
                float dot = p0 * d0 + p1 * d1 + p2 * d2;
                if (dot < 0.f) {
                    float g = NEG_COEF * dot / (d0 * d0 + d1 * d1 + d2 * d2 + LRELU_EPS);
                    p0 -= g * d0; p1 -= g * d1; p2 -= g * d2;
                }
                const int n = n0 + nb + h * 16 + ln;
                out[((size_t)(b * COUT + o) * 3 + 0) * NDIM + n] = p0;
                out[((size_t)(b * COUT + o) * 3 + 1) * NDIM + n] = p1;
                out[((size_t)(b * COUT + o) * 3 + 2) * NDIM + n] = p2;
            }
        }
    }
}

// ---------------------------------------------------------------------------
// FALLBACK PATH (ws too small): original verified kernels, unchanged.
// ---------------------------------------------------------------------------
__global__ __launch_bounds__(256) void vn_stats_mfma(
    const float* __restrict__ x, const unsigned short* __restrict__ wsu,
    float* __restrict__ stats)
{
    __shared__ unsigned short sXhi[192 * 40];
    __shared__ float redS[64], redQ[64];

    const int t  = threadIdx.x;
    const int n0 = blockIdx.x * 64;
    const int o0 = blockIdx.y * 64;
    const int b  = blockIdx.z;

    const int lane = t & 63;
    const int w    = t >> 6;
    const int q    = lane >> 4;
    const int ln   = lane & 15;

    const int jl = t & 31;
    const int kb = t >> 5;

    if (t < 64) { redS[t] = 0.f; redQ[t] = 0.f; }

    f32x4 acc[2][6];
    #pragma unroll
    for (int i = 0; i < 2; ++i)
        #pragma unroll
        for (int j = 0; j < 6; ++j) acc[i][j] = (f32x4)0.f;

    const unsigned short* wfh = wsu + WS_WFH;
    const int oo = o0 + (w >> 1) * 32;
    const int nb = (w & 1) * 32;

    for (int c0 = 0; c0 < CIN; c0 += 32) {
        __syncthreads();
        #pragma unroll
        for (int ip = 0; ip < 6; ++ip) {
            int jloc = ip * 32 + jl;
            int d = jloc >> 6, nl = jloc & 63;
            float v[4];
            #pragma unroll
            for (int i = 0; i < 4; ++i) {
                int c = c0 + kb + 8 * i;
                v[i] = x[((size_t)((b * CIN + c) * 3 + d)) * NDIM + n0 + nl];
            }
            unsigned p0 = (unsigned)f2bf(v[0]) | ((unsigned)f2bf(v[1]) << 16);
            unsigned p1 = (unsigned)f2bf(v[2]) | ((unsigned)f2bf(v[3]) << 16);
            *(uint2*)&sXhi[jloc * 40 + kb * 4] = make_uint2(p0, p1);
        }
        __syncthreads();
        bf16x8 af[2];
        #pragma unroll
        for (int mt = 0; mt < 2; ++mt)
            af[mt] = *(const bf16x8*)&wfh[(oo + mt * 16 + ln) * CIN + c0 + q * 8];
        #pragma unroll
        for (int nt = 0; nt < 6; ++nt) {
            int d = nt >> 1, h = nt & 1;
            int jloc = d * 64 + nb + h * 16 + ln;
            bf16x8 bh = *(const bf16x8*)&sXhi[jloc * 40 + q * 8];
            #pragma unroll
            for (int mt = 0; mt < 2; ++mt)
                acc[mt][nt] = __builtin_amdgcn_mfma_f32_16x16x32_bf16(af[mt], bh, acc[mt][nt], 0, 0, 0);
        }
    }

    #pragma unroll
    for (int mt = 0; mt < 2; ++mt) {
        #pragma unroll
        for (int r = 0; r < 4; ++r) {
            float s = 0.f, s2 = 0.f;
            #pragma unroll
            for (int h = 0; h < 2; ++h) {
                float p0 = acc[mt][0 + h][r];
                float p1 = acc[mt][2 + h][r];
                float p2 = acc[mt][4 + h][r];
                float n2 = p0 * p0 + p1 * p1 + p2 * p2;
                s += sqrtf(n2); s2 += n2;
            }
            #pragma unroll
            for (int m = 1; m < 16; m <<= 1) {
                s  += __shfl_xor(s,  m, 64);
                s2 += __shfl_xor(s2, m, 64);
            }
            if (ln == 0) {
                int ol = (w >> 1) * 32 + mt * 16 + q * 4 + r;
                atomicAdd(&redS[ol], s);
                atomicAdd(&redQ[ol], s2);
            }
        }
    }
    __syncthreads();
    if (t < 64) {
        int slot = blockIdx.x & (NSLOT - 1);
        atomicAdd(&stats[slot * 256 + o0 + t], redS[t]);
        atomicAdd(&stats[NSLOT * 256 + slot * 256 + o0 + t], redQ[t]);
    }
}

__global__ __launch_bounds__(256) void vn_main_mfma(
    const float* __restrict__ x, const unsigned short* __restrict__ wsu,
    const float* __restrict__ stats, const float* __restrict__ beta,
    float* __restrict__ out)
{
    __shared__ unsigned short sXhi[192 * 40];
    __shared__ unsigned short sXlo[192 * 40];

    const int t  = threadIdx.x;
    const int n0 = blockIdx.x * 64;
    const int o0 = blockIdx.y * 64;
    const int b  = blockIdx.z;

    const int lane = t & 63;
    const int w    = t >> 6;
    const int q    = lane >> 4;
    const int ln   = lane & 15;

    const int jl = t & 31;
    const int kb = t >> 5;

    f32x4 accP[2][6], accD[2][6];
    #pragma unroll
    for (int i = 0; i < 2; ++i)
        #pragma unroll
        for (int j = 0; j < 6; ++j) { accP[i][j] = (f32x4)0.f; accD[i][j] = (f32x4)0.f; }

    const unsigned short* wfh = wsu + WS_WFH;
    const unsigned short* wfl = wsu + WS_WFL;
    const unsigned short* wdh = wsu + WS_WDH;
    const unsigned short* wdl = wsu + WS_WDL;
    const int oo = o0 + (w >> 1) * 32;
    const int nb = (w & 1) * 32;

    for (int c0 = 0; c0 < CIN; c0 += 32) {
        __syncthreads();
        #pragma unroll
        for (int ip = 0; ip < 6; ++ip) {
            int jloc = ip * 32 + jl;
            int d = jloc >> 6, nl = jloc & 63;
            float v[4];
            #pragma unroll
            for (int i = 0; i < 4; ++i) {
                int c = c0 + kb + 8 * i;
                v[i] = x[((size_t)((b * CIN + c) * 3 + d)) * NDIM + n0 + nl];
            }
            unsigned short h0 = f2bf(v[0]), h1 = f2bf(v[1]), h2 = f2bf(v[2]), h3 = f2bf(v[3]);
            unsigned ph0 = (unsigned)h0 | ((unsigned)h1 << 16);
            unsigned ph1 = (unsigned)h2 | ((unsigned)h3 << 16);
            unsigned pl0 = (unsigned)f2bf(v[0] - bf2f(h0)) | ((unsigned)f2bf(v[1] - bf2f(h1)) << 16);
            unsigned pl1 = (unsigned)f2bf(v[2] - bf2f(h2)) | ((unsigned)f2bf(v[3] - bf2f(h3)) << 16);
            *(uint2*)&sXhi[jloc * 40 + kb * 4] = make_uint2(ph0, ph1);
            *(uint2*)&sXlo[jloc * 40 + kb * 4] = make_uint2(pl0, pl1);
        }
        __syncthreads();
        bf16x8 afh[2], afl[2], adh[2], adl[2];
        #pragma unroll
        for (int mt = 0; mt < 2; ++mt) {
            int row = (oo + mt * 16 + ln) * CIN + c0 + q * 8;
            afh[mt] = *(const bf16x8*)&wfh[row];
            afl[mt] = *(const bf16x8*)&wfl[row];
            adh[mt] = *(const bf16x8*)&wdh[row];
            adl[mt] = *(const bf16x8*)&wdl[row];
        }
        #pragma unroll
        for (int nt = 0; nt < 6; ++nt) {
            int d = nt >> 1, h = nt & 1;
            int jloc = d * 64 + nb + h * 16 + ln;
            bf16x8 bh = *(const bf16x8*)&sXhi[jloc * 40 + q * 8];
            bf16x8 bl = *(const bf16x8*)&sXlo[jloc * 40 + q * 8];
            #pragma unroll
            for (int mt = 0; mt < 2; ++mt) {
                f32x4 aP = accP[mt][nt];
                aP = __builtin_amdgcn_mfma_f32_16x16x32_bf16(afh[mt], bh, aP, 0, 0, 0);
                aP = __builtin_amdgcn_mfma_f32_16x16x32_bf16(afh[mt], bl, aP, 0, 0, 0);
                aP = __builtin_amdgcn_mfma_f32_16x16x32_bf16(afl[mt], bh, aP, 0, 0, 0);
                aP = __builtin_amdgcn_mfma_f32_16x16x32_bf16(afl[mt], bl, aP, 0, 0, 0);
                accP[mt][nt] = aP;
                f32x4 aD = accD[mt][nt];
                aD = __builtin_amdgcn_mfma_f32_16x16x32_bf16(adh[mt], bh, aD, 0, 0, 0);
                aD = __builtin_amdgcn_mfma_f32_16x16x32_bf16(adh[mt], bl, aD, 0, 0, 0);
                aD = __builtin_amdgcn_mfma_f32_16x16x32_bf16(adl[mt], bh, aD, 0, 0, 0);
                accD[mt][nt] = aD;
            }
        }
    }

    const float* meanp  = stats + 2 * NSLOT * 256;
    const float* scalep = meanp + 256;
    #pragma unroll
    for (int mt = 0; mt < 2; ++mt) {
        #pragma unroll
        for (int r = 0; r < 4; ++r) {
            const int o = oo + mt * 16 + q * 4 + r;
            const float mean  = meanp[o];
            const float scale = scalep[o];
            const float bet   = beta[o];
            #pragma unroll
            for (int h = 0; h < 2; ++h) {
                float p0 = accP[mt][0 + h][r], p1 = accP[mt][2 + h][r], p2 = accP[mt][4 + h][r];
                float d0 = accD[mt][0 + h][r], d1 = accD[mt][2 + h][r], d2 = accD[mt][4 + h][r];
                float n2 = p0 * p0 + p1 * p1 + p2 * p2;
                float nr = sqrtf(n2);
                float f  = ((nr - mean) * scale + bet) / nr;
                p0 *= f; p1 *= f; p2 *= f;
                float dot = p0 * d0 + p1 * d1 + p2 * d2;
                if (dot < 0.f) {
                    float g = NEG_COEF * dot / (d0 * d0 + d1 * d1 + d2 * d2 + LRELU_EPS);
                    p0 -= g * d0; p1 -= g * d1; p2 -= g * d2;
                }
                const int n = n0 + nb + h * 16 + ln;
                out[((size_t)(b * COUT + o) * 3 + 0) * NDIM + n] = p0;
                out[((size_t)(b * COUT + o) * 3 + 1) * NDIM + n] = p1;
                out[((size_t)(b * COUT + o) * 3 + 2) * NDIM + n] = p2;
            }
        }
    }
}

extern "C" void kernel_launch(void* const* d_in, const int* in_sizes, int n_in,
                              void* d_out, int out_size, void* d_ws, size_t ws_size,
                              hipStream_t stream) {
    const float* x     = (const float*)d_in[0];
    const float* Wf    = (const float*)d_in[1];
    const float* Wd    = (const float*)d_in[2];
    const float* gamma = (const float*)d_in[3];
    const float* beta  = (const float*)d_in[4];
    float* out = (float*)d_out;
    unsigned short* wsu = (unsigned short*)d_ws;
    float* stats = (float*)((char*)d_ws + WS_STATS_BYTE);

    hipMemsetAsync((char*)d_ws + WS_STATS_BYTE, 0, 2 * NSLOT * 256 * sizeof(float), stream);
    setup_w_kernel<<<dim3(256, 2), 256, 0, stream>>>(Wf, Wd, wsu);

    if (ws_size >= (size_t)WS_NEED) {
        char* xhp = (char*)d_ws + WS_XHI_BYTE;
        char* xlp = (char*)d_ws + WS_XLO_BYTE;
        vn_cvtstats<<<dim3(128, 1, 8), 512, 0, stream>>>(x, wsu, xhp, xlp, stats);
        vn_finalize2<<<1, 256, 0, stream>>>(stats, gamma);
        vn_main3<<<dim3(128, 4, 8), 256, 0, stream>>>(wsu, xhp, xlp, stats, beta, out);
    } else {
        dim3 grid(NDIM / 64, COUT / 64, BDIM);
        vn_stats_mfma<<<grid, 256, 0, stream>>>(x, wsu, stats);
        vn_finalize2<<<1, 256, 0, stream>>>(stats, gamma);
        vn_main_mfma<<<grid, 256, 0, stream>>>(x, wsu, stats, beta, out);
    }
}